// Round 1
// baseline (930.302 us; speedup 1.0000x reference)
//
#include <hip/hip_runtime.h>

#define NN 100000
#define NE 1600000
#define D 128
#define NC 8

// ---------------- utility ----------------
__global__ void k_zero(int* __restrict__ p, int n) {
    int i = blockIdx.x * blockDim.x + threadIdx.x;
    if (i < n) p[i] = 0;
}

// count in-degree (real edges only; self-loop handled implicitly)
__global__ void k_count(const int* __restrict__ dst, int* __restrict__ cnt, int E) {
    int e = blockIdx.x * blockDim.x + threadIdx.x;
    if (e < E) atomicAdd(&cnt[dst[e]], 1);
}

// ---------------- exclusive scan (3 kernels, 1024 elems/block) ----------------
__global__ void k_scan1(const int* __restrict__ in, int* __restrict__ out,
                        int* __restrict__ bsum, int n) {
    __shared__ int sd[256];
    int t = threadIdx.x;
    int base = blockIdx.x * 1024;
    int v[4], s = 0;
#pragma unroll
    for (int i = 0; i < 4; i++) {
        int idx = base + t * 4 + i;
        v[i] = (idx < n) ? in[idx] : 0;
        s += v[i];
    }
    sd[t] = s;
    __syncthreads();
    for (int off = 1; off < 256; off <<= 1) {
        int y = (t >= off) ? sd[t - off] : 0;
        __syncthreads();
        sd[t] += y;
        __syncthreads();
    }
    int run = sd[t] - s;  // exclusive offset for this thread
#pragma unroll
    for (int i = 0; i < 4; i++) {
        int idx = base + t * 4 + i;
        if (idx < n) out[idx] = run;
        run += v[i];
    }
    if (t == 255) bsum[blockIdx.x] = sd[255];
}

__global__ void k_scan2(int* __restrict__ bsum, int nb) {
    __shared__ int sd[256];
    int t = threadIdx.x;
    int v = (t < nb) ? bsum[t] : 0;
    sd[t] = v;
    __syncthreads();
    for (int off = 1; off < 256; off <<= 1) {
        int y = (t >= off) ? sd[t - off] : 0;
        __syncthreads();
        sd[t] += y;
        __syncthreads();
    }
    if (t < nb) bsum[t] = sd[t] - v;  // exclusive
}

__global__ void k_scan3(int* __restrict__ out, const int* __restrict__ bsum, int n) {
    int idx = blockIdx.x * blockDim.x + threadIdx.x;
    if (idx < n) out[idx] += bsum[idx >> 10];
}

__global__ void k_dinv(const int* __restrict__ cnt, float* __restrict__ dinv, int n) {
    int i = blockIdx.x * blockDim.x + threadIdx.x;
    if (i < n) dinv[i] = rsqrtf((float)(cnt[i] + 1));  // +1 = self-loop
}

__global__ void k_fill(const int* __restrict__ src, const int* __restrict__ dst,
                       const int* __restrict__ rowstart, int* __restrict__ cursor,
                       int* __restrict__ csr_src, int E) {
    int e = blockIdx.x * blockDim.x + threadIdx.x;
    if (e < E) {
        int d = dst[e];
        int pos = rowstart[d] + atomicAdd(&cursor[d], 1);
        csr_src[pos] = src[e];
    }
}

// ---------------- GEMM: out[r] = (A[r] @ W) * dinv[r] ----------------
// block tile 128x128, K=128 full; 256 threads, 8x8 per thread.
__global__ __launch_bounds__(256, 1) void k_gemm(const float* __restrict__ A,
                                                 const float* __restrict__ W,
                                                 const float* __restrict__ dinv,
                                                 float* __restrict__ out, int n) {
    __shared__ __align__(16) float xs[128][129];  // pad 1: conflict-free column reads
    __shared__ __align__(16) float ws[128][128];
    const int tid = threadIdx.x;
    const int r0g = blockIdx.x * 128;

    // stage W (128x128 = 4096 float4 / 256 threads = 16 each)
#pragma unroll
    for (int it = 0; it < 16; ++it) {
        int f = tid + it * 256;
        int r = f >> 5, c4 = (f & 31) << 2;
        float4 w4 = *(const float4*)&W[r * D + c4];
        *(float4*)&ws[r][c4] = w4;
    }
    // stage x tile (scalar LDS writes due to odd pad)
#pragma unroll
    for (int it = 0; it < 16; ++it) {
        int f = tid + it * 256;
        int r = f >> 5, c4 = (f & 31) << 2;
        int gr = r0g + r;
        float4 xv = make_float4(0.f, 0.f, 0.f, 0.f);
        if (gr < n) xv = *(const float4*)&A[(size_t)gr * D + c4];
        xs[r][c4] = xv.x; xs[r][c4 + 1] = xv.y; xs[r][c4 + 2] = xv.z; xs[r][c4 + 3] = xv.w;
    }
    __syncthreads();

    const int ty = tid >> 4, tx = tid & 15;
    const int r0 = ty * 8, c0 = tx * 8;
    float acc[8][8] = {};

#pragma unroll 4
    for (int k = 0; k < D; ++k) {
        float xv[8], wv[8];
#pragma unroll
        for (int j = 0; j < 8; ++j) xv[j] = xs[r0 + j][k];
        float4 wa = *(const float4*)&ws[k][c0];
        float4 wb = *(const float4*)&ws[k][c0 + 4];
        wv[0] = wa.x; wv[1] = wa.y; wv[2] = wa.z; wv[3] = wa.w;
        wv[4] = wb.x; wv[5] = wb.y; wv[6] = wb.z; wv[7] = wb.w;
#pragma unroll
        for (int i = 0; i < 8; ++i)
#pragma unroll
            for (int j = 0; j < 8; ++j) acc[i][j] += xv[i] * wv[j];
    }

#pragma unroll
    for (int i = 0; i < 8; ++i) {
        int gr = r0g + r0 + i;
        if (gr < n) {
            float s = dinv[gr];
            float4 o0, o1;
            o0.x = acc[i][0] * s; o0.y = acc[i][1] * s; o0.z = acc[i][2] * s; o0.w = acc[i][3] * s;
            o1.x = acc[i][4] * s; o1.y = acc[i][5] * s; o1.z = acc[i][6] * s; o1.w = acc[i][7] * s;
            *(float4*)&out[(size_t)gr * D + c0] = o0;
            *(float4*)&out[(size_t)gr * D + c0 + 4] = o1;
        }
    }
}

// ---------------- aggregation: out[i] = relu(dinv[i]*(hs[i] + sum_{s in in(i)} hs[s]) + b) ----
// 256 threads = 2 nodes/block, 128 threads per node (one per feature)
__global__ void k_agg(const float* __restrict__ hs, const int* __restrict__ rowstart,
                      const int* __restrict__ cnt, const int* __restrict__ csr_src,
                      const float* __restrict__ dinv, const float* __restrict__ bias,
                      float* __restrict__ out, int n) {
    int node = blockIdx.x * 2 + (threadIdx.x >> 7);
    int j = threadIdx.x & 127;
    if (node >= n) return;
    float acc = hs[(size_t)node * D + j];  // self-loop term
    int s0 = rowstart[node];
    int c = cnt[node];
    for (int t = 0; t < c; ++t) {
        int s = csr_src[s0 + t];
        acc += hs[(size_t)s * D + j];
    }
    float v = fmaf(dinv[node], acc, bias[j]);
    out[(size_t)node * D + j] = fmaxf(v, 0.0f);
}

// ---------------- output: softmax(h @ Wout + bout) ----------------
// 8 threads per node (one per class), 32 nodes per 256-thread block
__global__ void k_out(const float* __restrict__ h, const float* __restrict__ Wout,
                      const float* __restrict__ bout, float* __restrict__ out, int n) {
    __shared__ float ws[D * NC];
    int tid = threadIdx.x;
    for (int i = tid; i < D * NC; i += 256) ws[i] = Wout[i];
    __syncthreads();
    int node = blockIdx.x * 32 + (tid >> 3);
    int c = tid & 7;
    if (node >= n) return;
    float acc = bout[c];
    const float* hrow = &h[(size_t)node * D];
#pragma unroll
    for (int k4 = 0; k4 < 32; ++k4) {
        float4 hv = *(const float4*)&hrow[k4 * 4];
        acc += hv.x * ws[(k4 * 4 + 0) * NC + c] + hv.y * ws[(k4 * 4 + 1) * NC + c] +
               hv.z * ws[(k4 * 4 + 2) * NC + c] + hv.w * ws[(k4 * 4 + 3) * NC + c];
    }
    float m = acc;
#pragma unroll
    for (int off = 1; off < 8; off <<= 1) m = fmaxf(m, __shfl_xor(m, off));
    float e = __expf(acc - m);
    float ssum = e;
#pragma unroll
    for (int off = 1; off < 8; off <<= 1) ssum += __shfl_xor(ssum, off);
    out[(size_t)node * NC + c] = e / ssum;
}

// ---------------- launch ----------------
extern "C" void kernel_launch(void* const* d_in, const int* in_sizes, int n_in,
                              void* d_out, int out_size, void* d_ws, size_t ws_size,
                              hipStream_t stream) {
    const float* x    = (const float*)d_in[0];
    const int*   ei   = (const int*)d_in[1];   // [2][NE]: row 0 = src, row 1 = dst
    const float* W1   = (const float*)d_in[2];
    const float* b1   = (const float*)d_in[3];
    const float* W2   = (const float*)d_in[4];
    const float* b2   = (const float*)d_in[5];
    const float* Wout = (const float*)d_in[6];
    const float* bout = (const float*)d_in[7];
    float* out = (float*)d_out;

    size_t off = 0;
    char* base = (char*)d_ws;
    auto alloc = [&](size_t bytes) -> void* {
        void* p = base + off;
        off += (bytes + 255) & ~(size_t)255;
        return p;
    };
    int*   cnt      = (int*)alloc((size_t)NN * 4);
    int*   rowstart = (int*)alloc((size_t)NN * 4);
    int*   cursor   = (int*)alloc((size_t)NN * 4);
    int*   bsum     = (int*)alloc(1024);
    int*   csr      = (int*)alloc((size_t)NE * 4);
    float* dinv     = (float*)alloc((size_t)NN * 4);
    float* bufA     = (float*)alloc((size_t)NN * D * 4);
    float* bufB     = (float*)alloc((size_t)NN * D * 4);
    if (off > ws_size) return;  // workspace too small; fail visibly

    const int* src = ei;
    const int* dst = ei + NE;

    k_zero<<<(NN + 255) / 256, 256, 0, stream>>>(cnt, NN);
    k_zero<<<(NN + 255) / 256, 256, 0, stream>>>(cursor, NN);
    k_count<<<(NE + 255) / 256, 256, 0, stream>>>(dst, cnt, NE);

    int nb = (NN + 1023) / 1024;  // 98
    k_scan1<<<nb, 256, 0, stream>>>(cnt, rowstart, bsum, NN);
    k_scan2<<<1, 256, 0, stream>>>(bsum, nb);
    k_scan3<<<(NN + 255) / 256, 256, 0, stream>>>(rowstart, bsum, NN);
    k_dinv<<<(NN + 255) / 256, 256, 0, stream>>>(cnt, dinv, NN);
    k_fill<<<(NE + 255) / 256, 256, 0, stream>>>(src, dst, rowstart, cursor, csr, NE);

    int gemm_grid = (NN + 127) / 128;  // 782
    // layer 1
    k_gemm<<<gemm_grid, 256, 0, stream>>>(x, W1, dinv, bufA, NN);
    k_agg<<<(NN + 1) / 2, 256, 0, stream>>>(bufA, rowstart, cnt, csr, dinv, b1, bufB, NN);
    // layer 2
    k_gemm<<<gemm_grid, 256, 0, stream>>>(bufB, W2, dinv, bufA, NN);
    k_agg<<<(NN + 1) / 2, 256, 0, stream>>>(bufA, rowstart, cnt, csr, dinv, b2, bufB, NN);
    // output projection + softmax
    k_out<<<(NN + 31) / 32, 256, 0, stream>>>(bufB, Wout, bout, out, NN);
}

// Round 2
// 593.260 us; speedup vs baseline: 1.5681x; 1.5681x over previous
//
#include <hip/hip_runtime.h>

#define NN 100000
#define NE 1600000
#define D 128
#define NC 8

// ---------------- utility ----------------
__global__ void k_zero(int* __restrict__ p, int n) {
    int i = blockIdx.x * blockDim.x + threadIdx.x;
    if (i < n) p[i] = 0;
}

// count in-degree (real edges only; self-loop handled implicitly)
__global__ void k_count(const int* __restrict__ dst, int* __restrict__ cnt, int E) {
    int e = blockIdx.x * blockDim.x + threadIdx.x;
    if (e < E) atomicAdd(&cnt[dst[e]], 1);
}

// ---------------- exclusive scan (3 kernels, 1024 elems/block) ----------------
__global__ void k_scan1(const int* __restrict__ in, int* __restrict__ out,
                        int* __restrict__ bsum, int n) {
    __shared__ int sd[256];
    int t = threadIdx.x;
    int base = blockIdx.x * 1024;
    int v[4], s = 0;
#pragma unroll
    for (int i = 0; i < 4; i++) {
        int idx = base + t * 4 + i;
        v[i] = (idx < n) ? in[idx] : 0;
        s += v[i];
    }
    sd[t] = s;
    __syncthreads();
    for (int off = 1; off < 256; off <<= 1) {
        int y = (t >= off) ? sd[t - off] : 0;
        __syncthreads();
        sd[t] += y;
        __syncthreads();
    }
    int run = sd[t] - s;  // exclusive offset for this thread
#pragma unroll
    for (int i = 0; i < 4; i++) {
        int idx = base + t * 4 + i;
        if (idx < n) out[idx] = run;
        run += v[i];
    }
    if (t == 255) bsum[blockIdx.x] = sd[255];
}

__global__ void k_scan2(int* __restrict__ bsum, int nb) {
    __shared__ int sd[256];
    int t = threadIdx.x;
    int v = (t < nb) ? bsum[t] : 0;
    sd[t] = v;
    __syncthreads();
    for (int off = 1; off < 256; off <<= 1) {
        int y = (t >= off) ? sd[t - off] : 0;
        __syncthreads();
        sd[t] += y;
        __syncthreads();
    }
    if (t < nb) bsum[t] = sd[t] - v;  // exclusive
}

__global__ void k_scan3(int* __restrict__ out, const int* __restrict__ bsum, int n) {
    int idx = blockIdx.x * blockDim.x + threadIdx.x;
    if (idx < n) out[idx] += bsum[idx >> 10];
}

__global__ void k_dinv(const int* __restrict__ cnt, float* __restrict__ dinv, int n) {
    int i = blockIdx.x * blockDim.x + threadIdx.x;
    if (i < n) dinv[i] = rsqrtf((float)(cnt[i] + 1));  // +1 = self-loop
}

__global__ void k_fill(const int* __restrict__ src, const int* __restrict__ dst,
                       const int* __restrict__ rowstart, int* __restrict__ cursor,
                       int* __restrict__ csr_src, int E) {
    int e = blockIdx.x * blockDim.x + threadIdx.x;
    if (e < E) {
        int d = dst[e];
        int pos = rowstart[d] + atomicAdd(&cursor[d], 1);
        csr_src[pos] = src[e];
    }
}

// ---------------- GEMM: out[r] = (A[r] @ W) * dinv[r] ----------------
// block tile 128x128, K=128 full; 256 threads, 8x8 per thread.
__global__ __launch_bounds__(256, 1) void k_gemm(const float* __restrict__ A,
                                                 const float* __restrict__ W,
                                                 const float* __restrict__ dinv,
                                                 float* __restrict__ out, int n) {
    __shared__ __align__(16) float xs[128][129];  // pad 1: conflict-free column reads
    __shared__ __align__(16) float ws[128][128];
    const int tid = threadIdx.x;
    const int r0g = blockIdx.x * 128;

    // stage W (128x128 = 4096 float4 / 256 threads = 16 each)
#pragma unroll
    for (int it = 0; it < 16; ++it) {
        int f = tid + it * 256;
        int r = f >> 5, c4 = (f & 31) << 2;
        float4 w4 = *(const float4*)&W[r * D + c4];
        *(float4*)&ws[r][c4] = w4;
    }
    // stage x tile (scalar LDS writes due to odd pad)
#pragma unroll
    for (int it = 0; it < 16; ++it) {
        int f = tid + it * 256;
        int r = f >> 5, c4 = (f & 31) << 2;
        int gr = r0g + r;
        float4 xv = make_float4(0.f, 0.f, 0.f, 0.f);
        if (gr < n) xv = *(const float4*)&A[(size_t)gr * D + c4];
        xs[r][c4] = xv.x; xs[r][c4 + 1] = xv.y; xs[r][c4 + 2] = xv.z; xs[r][c4 + 3] = xv.w;
    }
    __syncthreads();

    const int ty = tid >> 4, tx = tid & 15;
    const int r0 = ty * 8, c0 = tx * 8;
    float acc[8][8] = {};

#pragma unroll 4
    for (int k = 0; k < D; ++k) {
        float xv[8], wv[8];
#pragma unroll
        for (int j = 0; j < 8; ++j) xv[j] = xs[r0 + j][k];
        float4 wa = *(const float4*)&ws[k][c0];
        float4 wb = *(const float4*)&ws[k][c0 + 4];
        wv[0] = wa.x; wv[1] = wa.y; wv[2] = wa.z; wv[3] = wa.w;
        wv[4] = wb.x; wv[5] = wb.y; wv[6] = wb.z; wv[7] = wb.w;
#pragma unroll
        for (int i = 0; i < 8; ++i)
#pragma unroll
            for (int j = 0; j < 8; ++j) acc[i][j] += xv[i] * wv[j];
    }

#pragma unroll
    for (int i = 0; i < 8; ++i) {
        int gr = r0g + r0 + i;
        if (gr < n) {
            float s = dinv[gr];
            float4 o0, o1;
            o0.x = acc[i][0] * s; o0.y = acc[i][1] * s; o0.z = acc[i][2] * s; o0.w = acc[i][3] * s;
            o1.x = acc[i][4] * s; o1.y = acc[i][5] * s; o1.z = acc[i][6] * s; o1.w = acc[i][7] * s;
            *(float4*)&out[(size_t)gr * D + c0] = o0;
            *(float4*)&out[(size_t)gr * D + c0 + 4] = o1;
        }
    }
}

// ---------------- aggregation v2: one wave per node, float4 lanes, 2-way half split,
// 4x unrolled neighbor loop => up to 8 neighbor rows in flight per wave.
// out[i] = relu(dinv[i]*(hs[i] + sum_{s in in(i)} hs[s]) + b)
__global__ __launch_bounds__(256) void k_agg(const float* __restrict__ hs,
                                             const int* __restrict__ rowstart,
                                             const int* __restrict__ cnt,
                                             const int* __restrict__ csr_src,
                                             const float* __restrict__ dinv,
                                             const float* __restrict__ bias,
                                             float* __restrict__ out, int n) {
    const int node = blockIdx.x * 4 + (threadIdx.x >> 6);
    if (node >= n) return;
    const int lane = threadIdx.x & 63;
    const int half = lane >> 5;        // 0 or 1: alternating neighbors
    const int j4 = (lane & 31) << 2;   // feature offset (float4 granularity)

    float4 acc = make_float4(0.f, 0.f, 0.f, 0.f);
    const size_t rowbase = (size_t)node * D + j4;
    if (half == 0) acc = *(const float4*)&hs[rowbase];  // self-loop term (once)

    const int c = cnt[node];
    const int* __restrict__ cl = csr_src + rowstart[node];

    int t = half;
    // main loop: 4 neighbors per half per iteration (8 rows in flight per wave)
    for (; t + 8 <= c; t += 8) {
        const int sA = cl[t];
        const int sB = cl[t + 2];
        const int sC = cl[t + 4];
        const int sD = cl[t + 6];
        const float4 vA = *(const float4*)&hs[(size_t)sA * D + j4];
        const float4 vB = *(const float4*)&hs[(size_t)sB * D + j4];
        const float4 vC = *(const float4*)&hs[(size_t)sC * D + j4];
        const float4 vD = *(const float4*)&hs[(size_t)sD * D + j4];
        acc.x += vA.x + vB.x + vC.x + vD.x;
        acc.y += vA.y + vB.y + vC.y + vD.y;
        acc.z += vA.z + vB.z + vC.z + vD.z;
        acc.w += vA.w + vB.w + vC.w + vD.w;
    }
    for (; t < c; t += 2) {
        const int s = cl[t];
        const float4 v = *(const float4*)&hs[(size_t)s * D + j4];
        acc.x += v.x; acc.y += v.y; acc.z += v.z; acc.w += v.w;
    }

    // combine the two halves (each holds the sum of its alternating neighbors)
    acc.x += __shfl_xor(acc.x, 32);
    acc.y += __shfl_xor(acc.y, 32);
    acc.z += __shfl_xor(acc.z, 32);
    acc.w += __shfl_xor(acc.w, 32);

    if (half == 0) {
        const float dv = dinv[node];
        const float4 bb = *(const float4*)&bias[j4];
        float4 o;
        o.x = fmaxf(fmaf(dv, acc.x, bb.x), 0.f);
        o.y = fmaxf(fmaf(dv, acc.y, bb.y), 0.f);
        o.z = fmaxf(fmaf(dv, acc.z, bb.z), 0.f);
        o.w = fmaxf(fmaf(dv, acc.w, bb.w), 0.f);
        *(float4*)&out[rowbase] = o;
    }
}

// ---------------- output: softmax(h @ Wout + bout) ----------------
// 8 threads per node (one per class), 32 nodes per 256-thread block
__global__ void k_out(const float* __restrict__ h, const float* __restrict__ Wout,
                      const float* __restrict__ bout, float* __restrict__ out, int n) {
    __shared__ float ws[D * NC];
    int tid = threadIdx.x;
    for (int i = tid; i < D * NC; i += 256) ws[i] = Wout[i];
    __syncthreads();
    int node = blockIdx.x * 32 + (tid >> 3);
    int c = tid & 7;
    if (node >= n) return;
    float acc = bout[c];
    const float* hrow = &h[(size_t)node * D];
#pragma unroll
    for (int k4 = 0; k4 < 32; ++k4) {
        float4 hv = *(const float4*)&hrow[k4 * 4];
        acc += hv.x * ws[(k4 * 4 + 0) * NC + c] + hv.y * ws[(k4 * 4 + 1) * NC + c] +
               hv.z * ws[(k4 * 4 + 2) * NC + c] + hv.w * ws[(k4 * 4 + 3) * NC + c];
    }
    float m = acc;
#pragma unroll
    for (int off = 1; off < 8; off <<= 1) m = fmaxf(m, __shfl_xor(m, off));
    float e = __expf(acc - m);
    float ssum = e;
#pragma unroll
    for (int off = 1; off < 8; off <<= 1) ssum += __shfl_xor(ssum, off);
    out[(size_t)node * NC + c] = e / ssum;
}

// ---------------- launch ----------------
extern "C" void kernel_launch(void* const* d_in, const int* in_sizes, int n_in,
                              void* d_out, int out_size, void* d_ws, size_t ws_size,
                              hipStream_t stream) {
    const float* x    = (const float*)d_in[0];
    const int*   ei   = (const int*)d_in[1];   // [2][NE]: row 0 = src, row 1 = dst
    const float* W1   = (const float*)d_in[2];
    const float* b1   = (const float*)d_in[3];
    const float* W2   = (const float*)d_in[4];
    const float* b2   = (const float*)d_in[5];
    const float* Wout = (const float*)d_in[6];
    const float* bout = (const float*)d_in[7];
    float* out = (float*)d_out;

    size_t off = 0;
    char* base = (char*)d_ws;
    auto alloc = [&](size_t bytes) -> void* {
        void* p = base + off;
        off += (bytes + 255) & ~(size_t)255;
        return p;
    };
    int*   cnt      = (int*)alloc((size_t)NN * 4);
    int*   rowstart = (int*)alloc((size_t)NN * 4);
    int*   cursor   = (int*)alloc((size_t)NN * 4);
    int*   bsum     = (int*)alloc(1024);
    int*   csr      = (int*)alloc((size_t)NE * 4);
    float* dinv     = (float*)alloc((size_t)NN * 4);
    float* bufA     = (float*)alloc((size_t)NN * D * 4);
    float* bufB     = (float*)alloc((size_t)NN * D * 4);
    if (off > ws_size) return;  // workspace too small; fail visibly

    const int* src = ei;
    const int* dst = ei + NE;

    k_zero<<<(NN + 255) / 256, 256, 0, stream>>>(cnt, NN);
    k_zero<<<(NN + 255) / 256, 256, 0, stream>>>(cursor, NN);
    k_count<<<(NE + 255) / 256, 256, 0, stream>>>(dst, cnt, NE);

    int nb = (NN + 1023) / 1024;  // 98
    k_scan1<<<nb, 256, 0, stream>>>(cnt, rowstart, bsum, NN);
    k_scan2<<<1, 256, 0, stream>>>(bsum, nb);
    k_scan3<<<(NN + 255) / 256, 256, 0, stream>>>(rowstart, bsum, NN);
    k_dinv<<<(NN + 255) / 256, 256, 0, stream>>>(cnt, dinv, NN);
    k_fill<<<(NE + 255) / 256, 256, 0, stream>>>(src, dst, rowstart, cursor, csr, NE);

    int gemm_grid = (NN + 127) / 128;  // 782
    // layer 1
    k_gemm<<<gemm_grid, 256, 0, stream>>>(x, W1, dinv, bufA, NN);
    k_agg<<<(NN + 3) / 4, 256, 0, stream>>>(bufA, rowstart, cnt, csr, dinv, b1, bufB, NN);
    // layer 2
    k_gemm<<<gemm_grid, 256, 0, stream>>>(bufB, W2, dinv, bufA, NN);
    k_agg<<<(NN + 3) / 4, 256, 0, stream>>>(bufA, rowstart, cnt, csr, dinv, b2, bufB, NN);
    // output projection + softmax
    k_out<<<(NN + 31) / 32, 256, 0, stream>>>(bufB, Wout, bout, out, NN);
}

// Round 3
// 515.535 us; speedup vs baseline: 1.8045x; 1.1508x over previous
//
#include <hip/hip_runtime.h>
#include <hip/hip_fp16.h>

#define NN 100000
#define NE 1600000
#define D 128
#define NC 8

// ---------------- utility ----------------
__global__ void k_zero(int* __restrict__ p, int n) {
    int i = blockIdx.x * blockDim.x + threadIdx.x;
    if (i < n) p[i] = 0;
}

// count in-degree, 4 edges/thread (int4 loads)
__global__ void k_count(const int* __restrict__ dst, int* __restrict__ cnt, int E) {
    int e0 = (blockIdx.x * blockDim.x + threadIdx.x) * 4;
    if (e0 >= E) return;  // E % 4 == 0, so full int4 is safe
    int4 d4 = *(const int4*)&dst[e0];
    atomicAdd(&cnt[d4.x], 1);
    atomicAdd(&cnt[d4.y], 1);
    atomicAdd(&cnt[d4.z], 1);
    atomicAdd(&cnt[d4.w], 1);
}

// ---------------- exclusive scan (3 kernels, 1024 elems/block) ----------------
__global__ void k_scan1(const int* __restrict__ in, int* __restrict__ out,
                        int* __restrict__ bsum, int n) {
    __shared__ int sd[256];
    int t = threadIdx.x;
    int base = blockIdx.x * 1024;
    int v[4], s = 0;
#pragma unroll
    for (int i = 0; i < 4; i++) {
        int idx = base + t * 4 + i;
        v[i] = (idx < n) ? in[idx] : 0;
        s += v[i];
    }
    sd[t] = s;
    __syncthreads();
    for (int off = 1; off < 256; off <<= 1) {
        int y = (t >= off) ? sd[t - off] : 0;
        __syncthreads();
        sd[t] += y;
        __syncthreads();
    }
    int run = sd[t] - s;  // exclusive offset for this thread
#pragma unroll
    for (int i = 0; i < 4; i++) {
        int idx = base + t * 4 + i;
        if (idx < n) out[idx] = run;
        run += v[i];
    }
    if (t == 255) bsum[blockIdx.x] = sd[255];
}

__global__ void k_scan2(int* __restrict__ bsum, int nb) {
    __shared__ int sd[256];
    int t = threadIdx.x;
    int v = (t < nb) ? bsum[t] : 0;
    sd[t] = v;
    __syncthreads();
    for (int off = 1; off < 256; off <<= 1) {
        int y = (t >= off) ? sd[t - off] : 0;
        __syncthreads();
        sd[t] += y;
        __syncthreads();
    }
    if (t < nb) bsum[t] = sd[t] - v;  // exclusive
}

// finalize rowstart AND initialize cursor = rowstart (saves a load in k_fill)
__global__ void k_scan3(int* __restrict__ out, int* __restrict__ cursor,
                        const int* __restrict__ bsum, int n) {
    int idx = blockIdx.x * blockDim.x + threadIdx.x;
    if (idx < n) {
        int v = out[idx] + bsum[idx >> 10];
        out[idx] = v;
        cursor[idx] = v;
    }
}

__global__ void k_dinv(const int* __restrict__ cnt, float* __restrict__ dinv, int n) {
    int i = blockIdx.x * blockDim.x + threadIdx.x;
    if (i < n) dinv[i] = rsqrtf((float)(cnt[i] + 1));  // +1 = self-loop
}

// fill CSR, 4 edges/thread; cursor pre-initialized to rowstart
__global__ void k_fill(const int* __restrict__ src, const int* __restrict__ dst,
                       int* __restrict__ cursor, int* __restrict__ csr_src, int E) {
    int e0 = (blockIdx.x * blockDim.x + threadIdx.x) * 4;
    if (e0 >= E) return;
    int4 d4 = *(const int4*)&dst[e0];
    int4 s4 = *(const int4*)&src[e0];
    int p0 = atomicAdd(&cursor[d4.x], 1);
    int p1 = atomicAdd(&cursor[d4.y], 1);
    int p2 = atomicAdd(&cursor[d4.z], 1);
    int p3 = atomicAdd(&cursor[d4.w], 1);
    csr_src[p0] = s4.x;
    csr_src[p1] = s4.y;
    csr_src[p2] = s4.z;
    csr_src[p3] = s4.w;
}

// ---------------- GEMM: hout[r] = half( (A[r] @ W) * dinv[r] ) ----------------
// block tile 128x128, K=128 full; 256 threads, 8x8 per thread; fp16 output.
__global__ __launch_bounds__(256, 1) void k_gemm(const float* __restrict__ A,
                                                 const float* __restrict__ W,
                                                 const float* __restrict__ dinv,
                                                 __half* __restrict__ hout, int n) {
    __shared__ __align__(16) float xs[128][129];  // pad 1: conflict-free column reads
    __shared__ __align__(16) float ws[128][128];
    const int tid = threadIdx.x;
    const int r0g = blockIdx.x * 128;

    // stage W (128x128 = 4096 float4 / 256 threads = 16 each)
#pragma unroll
    for (int it = 0; it < 16; ++it) {
        int f = tid + it * 256;
        int r = f >> 5, c4 = (f & 31) << 2;
        float4 w4 = *(const float4*)&W[r * D + c4];
        *(float4*)&ws[r][c4] = w4;
    }
    // stage x tile (scalar LDS writes due to odd pad)
#pragma unroll
    for (int it = 0; it < 16; ++it) {
        int f = tid + it * 256;
        int r = f >> 5, c4 = (f & 31) << 2;
        int gr = r0g + r;
        float4 xv = make_float4(0.f, 0.f, 0.f, 0.f);
        if (gr < n) xv = *(const float4*)&A[(size_t)gr * D + c4];
        xs[r][c4] = xv.x; xs[r][c4 + 1] = xv.y; xs[r][c4 + 2] = xv.z; xs[r][c4 + 3] = xv.w;
    }
    __syncthreads();

    const int ty = tid >> 4, tx = tid & 15;
    const int r0 = ty * 8, c0 = tx * 8;
    float acc[8][8] = {};

#pragma unroll 4
    for (int k = 0; k < D; ++k) {
        float xv[8], wv[8];
#pragma unroll
        for (int j = 0; j < 8; ++j) xv[j] = xs[r0 + j][k];
        float4 wa = *(const float4*)&ws[k][c0];
        float4 wb = *(const float4*)&ws[k][c0 + 4];
        wv[0] = wa.x; wv[1] = wa.y; wv[2] = wa.z; wv[3] = wa.w;
        wv[4] = wb.x; wv[5] = wb.y; wv[6] = wb.z; wv[7] = wb.w;
#pragma unroll
        for (int i = 0; i < 8; ++i)
#pragma unroll
            for (int j = 0; j < 8; ++j) acc[i][j] += xv[i] * wv[j];
    }

#pragma unroll
    for (int i = 0; i < 8; ++i) {
        int gr = r0g + r0 + i;
        if (gr < n) {
            float s = dinv[gr];
            union { float4 f; __half2 h[4]; } u;
#pragma unroll
            for (int q = 0; q < 4; ++q)
                u.h[q] = __floats2half2_rn(acc[i][2 * q] * s, acc[i][2 * q + 1] * s);
            *(float4*)&hout[(size_t)gr * D + c0] = u.f;
        }
    }
}

__device__ inline void add8h(float* acc, float4 raw) {
    const __half2* hp = (const __half2*)&raw;
#pragma unroll
    for (int q = 0; q < 4; ++q) {
        float2 f = __half22float2(hp[q]);
        acc[2 * q] += f.x;
        acc[2 * q + 1] += f.y;
    }
}

// ---------------- aggregation v3: fp16 gather, one wave per node ----------------
// 16 lanes cover a 128-half row (16B/lane); 4 neighbor-groups per wave; x4 unroll
// => up to 16 rows in flight per wave. out[i] = relu(dinv[i]*(self+sum_nb) + b)
template <typename OT>
__global__ __launch_bounds__(256) void k_agg(const __half* __restrict__ hs,
                                             const int* __restrict__ rowstart,
                                             const int* __restrict__ cnt,
                                             const int* __restrict__ csr_src,
                                             const float* __restrict__ dinv,
                                             const float* __restrict__ bias,
                                             OT* __restrict__ out, int n) {
    const int node = blockIdx.x * 4 + (threadIdx.x >> 6);
    if (node >= n) return;
    const int lane = threadIdx.x & 63;
    const int g = lane >> 4;           // neighbor group 0..3
    const int f8 = (lane & 15) << 3;   // feature offset (8 halves = 16B per lane)

    float acc[8] = {};
    if (g == 0) add8h(acc, *(const float4*)&hs[(size_t)node * D + f8]);  // self-loop

    const int c = cnt[node];
    const int* __restrict__ cl = csr_src + rowstart[node];

    int t = g;
    for (; t + 12 < c; t += 16) {
        const int s0 = cl[t];
        const int s1 = cl[t + 4];
        const int s2 = cl[t + 8];
        const int s3 = cl[t + 12];
        const float4 v0 = *(const float4*)&hs[(size_t)s0 * D + f8];
        const float4 v1 = *(const float4*)&hs[(size_t)s1 * D + f8];
        const float4 v2 = *(const float4*)&hs[(size_t)s2 * D + f8];
        const float4 v3 = *(const float4*)&hs[(size_t)s3 * D + f8];
        add8h(acc, v0); add8h(acc, v1); add8h(acc, v2); add8h(acc, v3);
    }
    for (; t < c; t += 4) {
        add8h(acc, *(const float4*)&hs[(size_t)cl[t] * D + f8]);
    }

    // combine the 4 groups
#pragma unroll
    for (int q = 0; q < 8; ++q) {
        acc[q] += __shfl_xor(acc[q], 16);
        acc[q] += __shfl_xor(acc[q], 32);
    }

    if (g == 0) {
        const float dv = dinv[node];
        float r[8];
#pragma unroll
        for (int q = 0; q < 8; ++q) r[q] = fmaxf(fmaf(dv, acc[q], bias[f8 + q]), 0.f);
        if constexpr (sizeof(OT) == 4) {
            float4 o0 = make_float4(r[0], r[1], r[2], r[3]);
            float4 o1 = make_float4(r[4], r[5], r[6], r[7]);
            *(float4*)&out[(size_t)node * D + f8] = o0;
            *(float4*)&out[(size_t)node * D + f8 + 4] = o1;
        } else {
            union { float4 f; __half2 h[4]; } u;
#pragma unroll
            for (int q = 0; q < 4; ++q) u.h[q] = __floats2half2_rn(r[2 * q], r[2 * q + 1]);
            *(float4*)&((__half*)out)[(size_t)node * D + f8] = u.f;
        }
    }
}

// ---------------- output: softmax(h @ Wout + bout), fp16 h ----------------
// 8 threads per node (one per class), 32 nodes per 256-thread block
__global__ void k_out(const __half* __restrict__ h, const float* __restrict__ Wout,
                      const float* __restrict__ bout, float* __restrict__ out, int n) {
    __shared__ float ws[D * NC];
    int tid = threadIdx.x;
    for (int i = tid; i < D * NC; i += 256) ws[i] = Wout[i];
    __syncthreads();
    int node = blockIdx.x * 32 + (tid >> 3);
    int c = tid & 7;
    if (node >= n) return;
    float acc = bout[c];
    const __half* hrow = &h[(size_t)node * D];
#pragma unroll
    for (int k8 = 0; k8 < 16; ++k8) {
        float4 raw = *(const float4*)&hrow[k8 * 8];
        const __half2* hp = (const __half2*)&raw;
#pragma unroll
        for (int q = 0; q < 4; ++q) {
            float2 f = __half22float2(hp[q]);
            int k = k8 * 8 + 2 * q;
            acc += f.x * ws[k * NC + c] + f.y * ws[(k + 1) * NC + c];
        }
    }
    float m = acc;
#pragma unroll
    for (int off = 1; off < 8; off <<= 1) m = fmaxf(m, __shfl_xor(m, off));
    float e = __expf(acc - m);
    float ssum = e;
#pragma unroll
    for (int off = 1; off < 8; off <<= 1) ssum += __shfl_xor(ssum, off);
    out[(size_t)node * NC + c] = e / ssum;
}

// ---------------- launch ----------------
extern "C" void kernel_launch(void* const* d_in, const int* in_sizes, int n_in,
                              void* d_out, int out_size, void* d_ws, size_t ws_size,
                              hipStream_t stream) {
    const float* x    = (const float*)d_in[0];
    const int*   ei   = (const int*)d_in[1];   // [2][NE]: row 0 = src, row 1 = dst
    const float* W1   = (const float*)d_in[2];
    const float* b1   = (const float*)d_in[3];
    const float* W2   = (const float*)d_in[4];
    const float* b2   = (const float*)d_in[5];
    const float* Wout = (const float*)d_in[6];
    const float* bout = (const float*)d_in[7];
    float* out = (float*)d_out;

    size_t off = 0;
    char* base = (char*)d_ws;
    auto alloc = [&](size_t bytes) -> void* {
        void* p = base + off;
        off += (bytes + 255) & ~(size_t)255;
        return p;
    };
    int*    cnt      = (int*)alloc((size_t)NN * 4);
    int*    rowstart = (int*)alloc((size_t)NN * 4);
    int*    cursor   = (int*)alloc((size_t)NN * 4);
    int*    bsum     = (int*)alloc(1024);
    int*    csr      = (int*)alloc((size_t)NE * 4);
    float*  dinv     = (float*)alloc((size_t)NN * 4);
    __half* h16a     = (__half*)alloc((size_t)NN * D * 2);
    __half* h16b     = (__half*)alloc((size_t)NN * D * 2);
    float*  bufF     = (float*)alloc((size_t)NN * D * 4);
    if (off > ws_size) return;  // workspace too small; fail visibly

    const int* src = ei;
    const int* dst = ei + NE;

    k_zero<<<(NN + 255) / 256, 256, 0, stream>>>(cnt, NN);
    k_count<<<(NE / 4 + 255) / 256, 256, 0, stream>>>(dst, cnt, NE);

    int nb = (NN + 1023) / 1024;  // 98
    k_scan1<<<nb, 256, 0, stream>>>(cnt, rowstart, bsum, NN);
    k_scan2<<<1, 256, 0, stream>>>(bsum, nb);
    k_scan3<<<(NN + 255) / 256, 256, 0, stream>>>(rowstart, cursor, bsum, NN);
    k_dinv<<<(NN + 255) / 256, 256, 0, stream>>>(cnt, dinv, NN);
    k_fill<<<(NE / 4 + 255) / 256, 256, 0, stream>>>(src, dst, cursor, csr, NE);

    int gemm_grid = (NN + 127) / 128;  // 782
    int agg_grid = (NN + 3) / 4;       // 25000
    // layer 1
    k_gemm<<<gemm_grid, 256, 0, stream>>>(x, W1, dinv, h16a, NN);
    k_agg<float><<<agg_grid, 256, 0, stream>>>(h16a, rowstart, cnt, csr, dinv, b1, bufF, NN);
    // layer 2
    k_gemm<<<gemm_grid, 256, 0, stream>>>(bufF, W2, dinv, h16a, NN);
    k_agg<__half><<<agg_grid, 256, 0, stream>>>(h16a, rowstart, cnt, csr, dinv, b2, h16b, NN);
    // output projection + softmax
    k_out<<<(NN + 31) / 32, 256, 0, stream>>>(h16b, Wout, bout, out, NN);
}

// Round 4
// 359.480 us; speedup vs baseline: 2.5879x; 1.4341x over previous
//
#include <hip/hip_runtime.h>
#include <hip/hip_fp16.h>

#define NN 100000
#define NE 1600000
#define D 128
#define NC 8
#define NBUCK 391   // ceil(NN / 256) buckets of 256 node-ids
#define CHUNK 4096  // edges per binning block

// ---------------- utility ----------------
__global__ void k_zero(int* __restrict__ p, int n) {
    int i = blockIdx.x * blockDim.x + threadIdx.x;
    if (i < n) p[i] = 0;
}

// ---------------- pass 0: global bucket histogram ----------------
__global__ __launch_bounds__(256) void k_bhist(const int* __restrict__ dst,
                                               int* __restrict__ gcount, int E) {
    __shared__ int h[NBUCK];
    for (int i = threadIdx.x; i < NBUCK; i += 256) h[i] = 0;
    __syncthreads();
    const int base0 = blockIdx.x * CHUNK;
#pragma unroll
    for (int i = 0; i < 4; ++i) {
        int e = base0 + i * 1024 + threadIdx.x * 4;
        if (e < E) {  // E % 4 == 0 -> full int4 safe
            int4 d4 = *(const int4*)&dst[e];
            atomicAdd(&h[d4.x >> 8], 1);
            atomicAdd(&h[d4.y >> 8], 1);
            atomicAdd(&h[d4.z >> 8], 1);
            atomicAdd(&h[d4.w >> 8], 1);
        }
    }
    __syncthreads();
    for (int i = threadIdx.x; i < NBUCK; i += 256) {
        int c = h[i];
        if (c) atomicAdd(&gcount[i], c);
    }
}

// ---------------- bucket scan (1 block, 512 threads) ----------------
__global__ void k_bscan(const int* __restrict__ gcount, int* __restrict__ bstart,
                        int* __restrict__ bcursor) {
    __shared__ int sd[512];
    int t = threadIdx.x;
    int v = (t < NBUCK) ? gcount[t] : 0;
    sd[t] = v;
    __syncthreads();
    for (int off = 1; off < 512; off <<= 1) {
        int y = (t >= off) ? sd[t - off] : 0;
        __syncthreads();
        sd[t] += y;
        __syncthreads();
    }
    int ex = sd[t] - v;  // exclusive prefix
    if (t <= NBUCK) bstart[t] = ex;   // bstart[NBUCK] == E
    if (t < NBUCK) bcursor[t] = ex;
}

// ---------------- pass 1: scatter edges into bucket-major staging ----------------
__global__ __launch_bounds__(256) void k_bscatter(const int* __restrict__ src,
                                                  const int* __restrict__ dst,
                                                  int* __restrict__ bcursor,
                                                  int2* __restrict__ staged, int E) {
    __shared__ int h[NBUCK];
    __shared__ int cur[NBUCK];
    const int t = threadIdx.x;
    for (int i = t; i < NBUCK; i += 256) h[i] = 0;
    __syncthreads();
    const int base0 = blockIdx.x * CHUNK;
    int4 d4[4], s4[4];
    bool val[4];
#pragma unroll
    for (int i = 0; i < 4; ++i) {
        int e = base0 + i * 1024 + t * 4;
        val[i] = e < E;
        if (val[i]) {
            d4[i] = *(const int4*)&dst[e];
            s4[i] = *(const int4*)&src[e];
            atomicAdd(&h[d4[i].x >> 8], 1);
            atomicAdd(&h[d4[i].y >> 8], 1);
            atomicAdd(&h[d4[i].z >> 8], 1);
            atomicAdd(&h[d4[i].w >> 8], 1);
        }
    }
    __syncthreads();
    // reserve a contiguous range per bucket for this block
    for (int i = t; i < NBUCK; i += 256) {
        int c = h[i];
        cur[i] = c ? atomicAdd(&bcursor[i], c) : 0;
    }
    __syncthreads();
#pragma unroll
    for (int i = 0; i < 4; ++i) {
        if (val[i]) {
            int p;
            p = atomicAdd(&cur[d4[i].x >> 8], 1); staged[p] = make_int2(s4[i].x, d4[i].x);
            p = atomicAdd(&cur[d4[i].y >> 8], 1); staged[p] = make_int2(s4[i].y, d4[i].y);
            p = atomicAdd(&cur[d4[i].z >> 8], 1); staged[p] = make_int2(s4[i].z, d4[i].z);
            p = atomicAdd(&cur[d4[i].w >> 8], 1); staged[p] = make_int2(s4[i].w, d4[i].w);
        }
    }
}

// ---------------- pass 2: per-bucket local CSR build (one block per bucket) ------
// also emits rowstart[], cnt[], dinv[] (coalesced), csr fill stays in a ~16KB
// L2-resident region -> full-line writebacks only.
__global__ __launch_bounds__(256) void k_bfill(const int2* __restrict__ staged,
                                               const int* __restrict__ bstart,
                                               int* __restrict__ rowstart,
                                               int* __restrict__ cnt,
                                               float* __restrict__ dinv,
                                               int* __restrict__ csr) {
    const int b = blockIdx.x;
    const int t = threadIdx.x;
    const int bs = bstart[b], be = bstart[b + 1];
    __shared__ int lc[256];  // per-node count, later reused as cursor
    __shared__ int ls[256];  // per-node global csr start
    __shared__ int sd[256];  // scan temp
    lc[t] = 0;
    __syncthreads();
    for (int i = bs + t; i < be; i += 256) {
        int2 e = staged[i];
        atomicAdd(&lc[e.y & 255], 1);
    }
    __syncthreads();
    int v = lc[t];
    sd[t] = v;
    __syncthreads();
    for (int off = 1; off < 256; off <<= 1) {
        int y = (t >= off) ? sd[t - off] : 0;
        __syncthreads();
        sd[t] += y;
        __syncthreads();
    }
    int ex = sd[t] - v;
    ls[t] = bs + ex;
    int node = (b << 8) + t;
    if (node < NN) {
        rowstart[node] = bs + ex;
        cnt[node] = v;
        dinv[node] = rsqrtf((float)(v + 1));  // +1 = self-loop
    }
    lc[t] = 0;  // reuse as cursor
    __syncthreads();
    for (int i = bs + t; i < be; i += 256) {
        int2 e = staged[i];
        int li = e.y & 255;
        int p = atomicAdd(&lc[li], 1);
        csr[ls[li] + p] = e.x;
    }
}

// ---------------- GEMM: hout[r] = half( (A[r] @ W) * dinv[r] ) ----------------
// block tile 128x128, K=128 full; 256 threads, 8x8 per thread; fp16 output.
__global__ __launch_bounds__(256, 1) void k_gemm(const float* __restrict__ A,
                                                 const float* __restrict__ W,
                                                 const float* __restrict__ dinv,
                                                 __half* __restrict__ hout, int n) {
    __shared__ __align__(16) float xs[128][129];  // pad 1: conflict-free column reads
    __shared__ __align__(16) float ws[128][128];
    const int tid = threadIdx.x;
    const int r0g = blockIdx.x * 128;

    // stage W (128x128 = 4096 float4 / 256 threads = 16 each)
#pragma unroll
    for (int it = 0; it < 16; ++it) {
        int f = tid + it * 256;
        int r = f >> 5, c4 = (f & 31) << 2;
        float4 w4 = *(const float4*)&W[r * D + c4];
        *(float4*)&ws[r][c4] = w4;
    }
    // stage x tile (scalar LDS writes due to odd pad)
#pragma unroll
    for (int it = 0; it < 16; ++it) {
        int f = tid + it * 256;
        int r = f >> 5, c4 = (f & 31) << 2;
        int gr = r0g + r;
        float4 xv = make_float4(0.f, 0.f, 0.f, 0.f);
        if (gr < n) xv = *(const float4*)&A[(size_t)gr * D + c4];
        xs[r][c4] = xv.x; xs[r][c4 + 1] = xv.y; xs[r][c4 + 2] = xv.z; xs[r][c4 + 3] = xv.w;
    }
    __syncthreads();

    const int ty = tid >> 4, tx = tid & 15;
    const int r0 = ty * 8, c0 = tx * 8;
    float acc[8][8] = {};

#pragma unroll 4
    for (int k = 0; k < D; ++k) {
        float xv[8], wv[8];
#pragma unroll
        for (int j = 0; j < 8; ++j) xv[j] = xs[r0 + j][k];
        float4 wa = *(const float4*)&ws[k][c0];
        float4 wb = *(const float4*)&ws[k][c0 + 4];
        wv[0] = wa.x; wv[1] = wa.y; wv[2] = wa.z; wv[3] = wa.w;
        wv[4] = wb.x; wv[5] = wb.y; wv[6] = wb.z; wv[7] = wb.w;
#pragma unroll
        for (int i = 0; i < 8; ++i)
#pragma unroll
            for (int j = 0; j < 8; ++j) acc[i][j] += xv[i] * wv[j];
    }

#pragma unroll
    for (int i = 0; i < 8; ++i) {
        int gr = r0g + r0 + i;
        if (gr < n) {
            float s = dinv[gr];
            union { float4 f; __half2 h[4]; } u;
#pragma unroll
            for (int q = 0; q < 4; ++q)
                u.h[q] = __floats2half2_rn(acc[i][2 * q] * s, acc[i][2 * q + 1] * s);
            *(float4*)&hout[(size_t)gr * D + c0] = u.f;
        }
    }
}

__device__ inline void add8h(float* acc, float4 raw) {
    const __half2* hp = (const __half2*)&raw;
#pragma unroll
    for (int q = 0; q < 4; ++q) {
        float2 f = __half22float2(hp[q]);
        acc[2 * q] += f.x;
        acc[2 * q + 1] += f.y;
    }
}

// ---------------- aggregation: fp16 gather, one wave per node ----------------
// 16 lanes cover a 128-half row (16B/lane); 4 neighbor-groups per wave; x4 unroll
// => up to 16 rows in flight per wave. out[i] = relu(dinv[i]*(self+sum_nb) + b)
template <typename OT>
__global__ __launch_bounds__(256) void k_agg(const __half* __restrict__ hs,
                                             const int* __restrict__ rowstart,
                                             const int* __restrict__ cnt,
                                             const int* __restrict__ csr_src,
                                             const float* __restrict__ dinv,
                                             const float* __restrict__ bias,
                                             OT* __restrict__ out, int n) {
    const int node = blockIdx.x * 4 + (threadIdx.x >> 6);
    if (node >= n) return;
    const int lane = threadIdx.x & 63;
    const int g = lane >> 4;           // neighbor group 0..3
    const int f8 = (lane & 15) << 3;   // feature offset (8 halves = 16B per lane)

    float acc[8] = {};
    if (g == 0) add8h(acc, *(const float4*)&hs[(size_t)node * D + f8]);  // self-loop

    const int c = cnt[node];
    const int* __restrict__ cl = csr_src + rowstart[node];

    int t = g;
    for (; t + 12 < c; t += 16) {
        const int s0 = cl[t];
        const int s1 = cl[t + 4];
        const int s2 = cl[t + 8];
        const int s3 = cl[t + 12];
        const float4 v0 = *(const float4*)&hs[(size_t)s0 * D + f8];
        const float4 v1 = *(const float4*)&hs[(size_t)s1 * D + f8];
        const float4 v2 = *(const float4*)&hs[(size_t)s2 * D + f8];
        const float4 v3 = *(const float4*)&hs[(size_t)s3 * D + f8];
        add8h(acc, v0); add8h(acc, v1); add8h(acc, v2); add8h(acc, v3);
    }
    for (; t < c; t += 4) {
        add8h(acc, *(const float4*)&hs[(size_t)cl[t] * D + f8]);
    }

    // combine the 4 groups
#pragma unroll
    for (int q = 0; q < 8; ++q) {
        acc[q] += __shfl_xor(acc[q], 16);
        acc[q] += __shfl_xor(acc[q], 32);
    }

    if (g == 0) {
        const float dv = dinv[node];
        float r[8];
#pragma unroll
        for (int q = 0; q < 8; ++q) r[q] = fmaxf(fmaf(dv, acc[q], bias[f8 + q]), 0.f);
        if constexpr (sizeof(OT) == 4) {
            float4 o0 = make_float4(r[0], r[1], r[2], r[3]);
            float4 o1 = make_float4(r[4], r[5], r[6], r[7]);
            *(float4*)&out[(size_t)node * D + f8] = o0;
            *(float4*)&out[(size_t)node * D + f8 + 4] = o1;
        } else {
            union { float4 f; __half2 h[4]; } u;
#pragma unroll
            for (int q = 0; q < 4; ++q) u.h[q] = __floats2half2_rn(r[2 * q], r[2 * q + 1]);
            *(float4*)&((__half*)out)[(size_t)node * D + f8] = u.f;
        }
    }
}

// ---------------- output: softmax(h @ Wout + bout), fp16 h ----------------
// 8 threads per node (one per class), 32 nodes per 256-thread block
__global__ void k_out(const __half* __restrict__ h, const float* __restrict__ Wout,
                      const float* __restrict__ bout, float* __restrict__ out, int n) {
    __shared__ float ws[D * NC];
    int tid = threadIdx.x;
    for (int i = tid; i < D * NC; i += 256) ws[i] = Wout[i];
    __syncthreads();
    int node = blockIdx.x * 32 + (tid >> 3);
    int c = tid & 7;
    if (node >= n) return;
    float acc = bout[c];
    const __half* hrow = &h[(size_t)node * D];
#pragma unroll
    for (int k8 = 0; k8 < 16; ++k8) {
        float4 raw = *(const float4*)&hrow[k8 * 8];
        const __half2* hp = (const __half2*)&raw;
#pragma unroll
        for (int q = 0; q < 4; ++q) {
            float2 f = __half22float2(hp[q]);
            int k = k8 * 8 + 2 * q;
            acc += f.x * ws[k * NC + c] + f.y * ws[(k + 1) * NC + c];
        }
    }
    float m = acc;
#pragma unroll
    for (int off = 1; off < 8; off <<= 1) m = fmaxf(m, __shfl_xor(m, off));
    float e = __expf(acc - m);
    float ssum = e;
#pragma unroll
    for (int off = 1; off < 8; off <<= 1) ssum += __shfl_xor(ssum, off);
    out[(size_t)node * NC + c] = e / ssum;
}

// ---------------- launch ----------------
extern "C" void kernel_launch(void* const* d_in, const int* in_sizes, int n_in,
                              void* d_out, int out_size, void* d_ws, size_t ws_size,
                              hipStream_t stream) {
    const float* x    = (const float*)d_in[0];
    const int*   ei   = (const int*)d_in[1];   // [2][NE]: row 0 = src, row 1 = dst
    const float* W1   = (const float*)d_in[2];
    const float* b1   = (const float*)d_in[3];
    const float* W2   = (const float*)d_in[4];
    const float* b2   = (const float*)d_in[5];
    const float* Wout = (const float*)d_in[6];
    const float* bout = (const float*)d_in[7];
    float* out = (float*)d_out;

    size_t off = 0;
    char* base = (char*)d_ws;
    auto alloc = [&](size_t bytes) -> void* {
        void* p = base + off;
        off += (bytes + 255) & ~(size_t)255;
        return p;
    };
    int*    cnt      = (int*)alloc((size_t)NN * 4);
    int*    rowstart = (int*)alloc((size_t)NN * 4);
    int*    gcount   = (int*)alloc((size_t)(NBUCK + 1) * 4);
    int*    bstart   = (int*)alloc((size_t)(NBUCK + 1) * 4);
    int*    bcursor  = (int*)alloc((size_t)(NBUCK + 1) * 4);
    int*    csr      = (int*)alloc((size_t)NE * 4);
    float*  dinv     = (float*)alloc((size_t)NN * 4);
    __half* h16a     = (__half*)alloc((size_t)NN * D * 2);
    __half* h16b     = (__half*)alloc((size_t)NN * D * 2);
    float*  bufF     = (float*)alloc((size_t)NN * D * 4);
    int2*   staged   = (int2*)bufF;  // alias: staged is dead before bufF is written
    if (off > ws_size) return;  // workspace too small; fail visibly

    const int* src = ei;
    const int* dst = ei + NE;

    // ---- CSR build via bucketed counting sort ----
    int bin_grid = (NE + CHUNK - 1) / CHUNK;  // 391
    k_zero<<<2, 256, 0, stream>>>(gcount, NBUCK);
    k_bhist<<<bin_grid, 256, 0, stream>>>(dst, gcount, NE);
    k_bscan<<<1, 512, 0, stream>>>(gcount, bstart, bcursor);
    k_bscatter<<<bin_grid, 256, 0, stream>>>(src, dst, bcursor, staged, NE);
    k_bfill<<<NBUCK, 256, 0, stream>>>(staged, bstart, rowstart, cnt, dinv, csr);

    int gemm_grid = (NN + 127) / 128;  // 782
    int agg_grid = (NN + 3) / 4;       // 25000
    // layer 1
    k_gemm<<<gemm_grid, 256, 0, stream>>>(x, W1, dinv, h16a, NN);
    k_agg<float><<<agg_grid, 256, 0, stream>>>(h16a, rowstart, cnt, csr, dinv, b1, bufF, NN);
    // layer 2
    k_gemm<<<gemm_grid, 256, 0, stream>>>(bufF, W2, dinv, h16a, NN);
    k_agg<__half><<<agg_grid, 256, 0, stream>>>(h16a, rowstart, cnt, csr, dinv, b2, h16b, NN);
    // output projection + softmax
    k_out<<<(NN + 31) / 32, 256, 0, stream>>>(h16b, Wout, bout, out, NN);
}

// Round 5
// 303.134 us; speedup vs baseline: 3.0689x; 1.1859x over previous
//
#include <hip/hip_runtime.h>
#include <hip/hip_fp16.h>

#define NN 100000
#define NE 1600000
#define D 128
#define NC 8
#define NBUCK 391   // ceil(NN / 256) buckets of 256 node-ids
#define CHUNK 4096  // edges per binning block

typedef _Float16 half8 __attribute__((ext_vector_type(8)));
typedef float f32x4 __attribute__((ext_vector_type(4)));

// ---------------- utility ----------------
__global__ void k_zero(int* __restrict__ p, int n) {
    int i = blockIdx.x * blockDim.x + threadIdx.x;
    if (i < n) p[i] = 0;
}

// ---------------- pass 0: global bucket histogram ----------------
__global__ __launch_bounds__(256) void k_bhist(const int* __restrict__ dst,
                                               int* __restrict__ gcount, int E) {
    __shared__ int h[NBUCK];
    for (int i = threadIdx.x; i < NBUCK; i += 256) h[i] = 0;
    __syncthreads();
    const int base0 = blockIdx.x * CHUNK;
#pragma unroll
    for (int i = 0; i < 4; ++i) {
        int e = base0 + i * 1024 + threadIdx.x * 4;
        if (e < E) {  // E % 4 == 0 -> full int4 safe
            int4 d4 = *(const int4*)&dst[e];
            atomicAdd(&h[d4.x >> 8], 1);
            atomicAdd(&h[d4.y >> 8], 1);
            atomicAdd(&h[d4.z >> 8], 1);
            atomicAdd(&h[d4.w >> 8], 1);
        }
    }
    __syncthreads();
    for (int i = threadIdx.x; i < NBUCK; i += 256) {
        int c = h[i];
        if (c) atomicAdd(&gcount[i], c);
    }
}

// ---------------- bucket scan (1 block, 512 threads) ----------------
__global__ void k_bscan(const int* __restrict__ gcount, int* __restrict__ bstart,
                        int* __restrict__ bcursor) {
    __shared__ int sd[512];
    int t = threadIdx.x;
    int v = (t < NBUCK) ? gcount[t] : 0;
    sd[t] = v;
    __syncthreads();
    for (int off = 1; off < 512; off <<= 1) {
        int y = (t >= off) ? sd[t - off] : 0;
        __syncthreads();
        sd[t] += y;
        __syncthreads();
    }
    int ex = sd[t] - v;  // exclusive prefix
    if (t <= NBUCK) bstart[t] = ex;   // bstart[NBUCK] == E
    if (t < NBUCK) bcursor[t] = ex;
}

// ---------------- pass 1: scatter edges into bucket-major staging ----------------
__global__ __launch_bounds__(256) void k_bscatter(const int* __restrict__ src,
                                                  const int* __restrict__ dst,
                                                  int* __restrict__ bcursor,
                                                  int2* __restrict__ staged, int E) {
    __shared__ int h[NBUCK];
    __shared__ int cur[NBUCK];
    const int t = threadIdx.x;
    for (int i = t; i < NBUCK; i += 256) h[i] = 0;
    __syncthreads();
    const int base0 = blockIdx.x * CHUNK;
    int4 d4[4], s4[4];
    bool val[4];
#pragma unroll
    for (int i = 0; i < 4; ++i) {
        int e = base0 + i * 1024 + t * 4;
        val[i] = e < E;
        if (val[i]) {
            d4[i] = *(const int4*)&dst[e];
            s4[i] = *(const int4*)&src[e];
            atomicAdd(&h[d4[i].x >> 8], 1);
            atomicAdd(&h[d4[i].y >> 8], 1);
            atomicAdd(&h[d4[i].z >> 8], 1);
            atomicAdd(&h[d4[i].w >> 8], 1);
        }
    }
    __syncthreads();
    // reserve a contiguous range per bucket for this block
    for (int i = t; i < NBUCK; i += 256) {
        int c = h[i];
        cur[i] = c ? atomicAdd(&bcursor[i], c) : 0;
    }
    __syncthreads();
#pragma unroll
    for (int i = 0; i < 4; ++i) {
        if (val[i]) {
            int p;
            p = atomicAdd(&cur[d4[i].x >> 8], 1); staged[p] = make_int2(s4[i].x, d4[i].x);
            p = atomicAdd(&cur[d4[i].y >> 8], 1); staged[p] = make_int2(s4[i].y, d4[i].y);
            p = atomicAdd(&cur[d4[i].z >> 8], 1); staged[p] = make_int2(s4[i].z, d4[i].z);
            p = atomicAdd(&cur[d4[i].w >> 8], 1); staged[p] = make_int2(s4[i].w, d4[i].w);
        }
    }
}

// ---------------- pass 2: per-bucket local CSR build (one block per bucket) ------
__global__ __launch_bounds__(256) void k_bfill(const int2* __restrict__ staged,
                                               const int* __restrict__ bstart,
                                               int* __restrict__ rowstart,
                                               int* __restrict__ cnt,
                                               float* __restrict__ dinv,
                                               int* __restrict__ csr) {
    const int b = blockIdx.x;
    const int t = threadIdx.x;
    const int bs = bstart[b], be = bstart[b + 1];
    __shared__ int lc[256];  // per-node count, later reused as cursor
    __shared__ int ls[256];  // per-node global csr start
    __shared__ int sd[256];  // scan temp
    lc[t] = 0;
    __syncthreads();
    for (int i = bs + t; i < be; i += 256) {
        int2 e = staged[i];
        atomicAdd(&lc[e.y & 255], 1);
    }
    __syncthreads();
    int v = lc[t];
    sd[t] = v;
    __syncthreads();
    for (int off = 1; off < 256; off <<= 1) {
        int y = (t >= off) ? sd[t - off] : 0;
        __syncthreads();
        sd[t] += y;
        __syncthreads();
    }
    int ex = sd[t] - v;
    ls[t] = bs + ex;
    int node = (b << 8) + t;
    if (node < NN) {
        rowstart[node] = bs + ex;
        cnt[node] = v;
        dinv[node] = rsqrtf((float)(v + 1));  // +1 = self-loop
    }
    lc[t] = 0;  // reuse as cursor
    __syncthreads();
    for (int i = bs + t; i < be; i += 256) {
        int2 e = staged[i];
        int li = e.y & 255;
        int p = atomicAdd(&lc[li], 1);
        csr[ls[li] + p] = e.x;
    }
}

// ---------------- W convert+transpose: wt[col][k] = half(W[k][col]) ----------------
__global__ void k_cvtw(const float* __restrict__ W, __half* __restrict__ wt) {
    int t = threadIdx.x;
    for (int i = t; i < D * D; i += 256) {
        int k = i >> 7, c = i & 127;
        wt[c * D + k] = __float2half(W[i]);
    }
}

// ---------------- MFMA GEMM: hout[r] = half( (A[r] @ W) * dinv[r] ) ----------------
// 4 waves/block; wave = 16 rows x 64 cols (4 col-tiles x 4 K-steps of 16x16x32).
// Block = 32 rows x 128 cols. NN = 3125*32 exactly -> no row guards.
// A-frag: row = lane&15, k = (lane>>4)*8 + j (contiguous 16B). B from W^T likewise.
// D-frag: col = lane&15, row = (lane>>4)*4 + reg.
template <bool F32IN>
__global__ __launch_bounds__(256) void k_mgemm(const void* __restrict__ Ain,
                                               const __half* __restrict__ wt,
                                               const float* __restrict__ dinv,
                                               __half* __restrict__ hout) {
    const int tid = threadIdx.x;
    const int lane = tid & 63;
    const int wave = tid >> 6;
    const int wr = wave >> 1, wc = wave & 1;
    const int row0 = blockIdx.x * 32 + wr * 16;
    const int arow = row0 + (lane & 15);
    const int kg = lane >> 4;

    half8 afrag[4];
    if constexpr (F32IN) {
        const float* A = (const float*)Ain;
#pragma unroll
        for (int s = 0; s < 4; ++s) {
            const float* p = &A[(size_t)arow * D + s * 32 + kg * 8];
            float4 f0 = *(const float4*)p;
            float4 f1 = *(const float4*)(p + 4);
            half8 a;
            a[0] = (_Float16)f0.x; a[1] = (_Float16)f0.y;
            a[2] = (_Float16)f0.z; a[3] = (_Float16)f0.w;
            a[4] = (_Float16)f1.x; a[5] = (_Float16)f1.y;
            a[6] = (_Float16)f1.z; a[7] = (_Float16)f1.w;
            afrag[s] = a;
        }
    } else {
        const __half* A = (const __half*)Ain;
#pragma unroll
        for (int s = 0; s < 4; ++s)
            afrag[s] = *(const half8*)&A[(size_t)arow * D + s * 32 + kg * 8];
    }

    f32x4 acc[4] = {};
    const int colbase = wc * 64;
#pragma unroll
    for (int c = 0; c < 4; ++c) {
        const int col = colbase + c * 16 + (lane & 15);
#pragma unroll
        for (int s = 0; s < 4; ++s) {
            half8 b = *(const half8*)&wt[col * D + s * 32 + kg * 8];
            acc[c] = __builtin_amdgcn_mfma_f32_16x16x32_f16(afrag[s], b, acc[c], 0, 0, 0);
        }
    }

#pragma unroll
    for (int r = 0; r < 4; ++r) {
        const int row = row0 + kg * 4 + r;
        const float dv = dinv[row];
#pragma unroll
        for (int c = 0; c < 4; ++c) {
            const int col = colbase + c * 16 + (lane & 15);
            hout[(size_t)row * D + col] = __float2half(acc[c][r] * dv);
        }
    }
}

__device__ inline void add8h(float* acc, float4 raw) {
    const __half2* hp = (const __half2*)&raw;
#pragma unroll
    for (int q = 0; q < 4; ++q) {
        float2 f = __half22float2(hp[q]);
        acc[2 * q] += f.x;
        acc[2 * q + 1] += f.y;
    }
}

// ---------------- aggregation: fp16 gather, one wave per node ----------------
// 16 lanes cover a 128-half row (16B/lane); 4 neighbor-groups per wave; x4 unroll
// => up to 16 rows in flight per wave. out[i] = relu(dinv[i]*(self+sum_nb) + b)
__global__ __launch_bounds__(256) void k_agg(const __half* __restrict__ hs,
                                             const int* __restrict__ rowstart,
                                             const int* __restrict__ cnt,
                                             const int* __restrict__ csr_src,
                                             const float* __restrict__ dinv,
                                             const float* __restrict__ bias,
                                             __half* __restrict__ out, int n) {
    const int node = blockIdx.x * 4 + (threadIdx.x >> 6);
    if (node >= n) return;
    const int lane = threadIdx.x & 63;
    const int g = lane >> 4;           // neighbor group 0..3
    const int f8 = (lane & 15) << 3;   // feature offset (8 halves = 16B per lane)

    float acc[8] = {};
    if (g == 0) add8h(acc, *(const float4*)&hs[(size_t)node * D + f8]);  // self-loop

    const int c = cnt[node];
    const int* __restrict__ cl = csr_src + rowstart[node];

    int t = g;
    for (; t + 12 < c; t += 16) {
        const int s0 = cl[t];
        const int s1 = cl[t + 4];
        const int s2 = cl[t + 8];
        const int s3 = cl[t + 12];
        const float4 v0 = *(const float4*)&hs[(size_t)s0 * D + f8];
        const float4 v1 = *(const float4*)&hs[(size_t)s1 * D + f8];
        const float4 v2 = *(const float4*)&hs[(size_t)s2 * D + f8];
        const float4 v3 = *(const float4*)&hs[(size_t)s3 * D + f8];
        add8h(acc, v0); add8h(acc, v1); add8h(acc, v2); add8h(acc, v3);
    }
    for (; t < c; t += 4) {
        add8h(acc, *(const float4*)&hs[(size_t)cl[t] * D + f8]);
    }

    // combine the 4 groups
#pragma unroll
    for (int q = 0; q < 8; ++q) {
        acc[q] += __shfl_xor(acc[q], 16);
        acc[q] += __shfl_xor(acc[q], 32);
    }

    if (g == 0) {
        const float dv = dinv[node];
        float r[8];
#pragma unroll
        for (int q = 0; q < 8; ++q) r[q] = fmaxf(fmaf(dv, acc[q], bias[f8 + q]), 0.f);
        union { float4 f; __half2 h[4]; } u;
#pragma unroll
        for (int q = 0; q < 4; ++q) u.h[q] = __floats2half2_rn(r[2 * q], r[2 * q + 1]);
        *(float4*)&out[(size_t)node * D + f8] = u.f;
    }
}

// ---------------- output: softmax(h @ Wout + bout), fp16 h ----------------
__global__ void k_out(const __half* __restrict__ h, const float* __restrict__ Wout,
                      const float* __restrict__ bout, float* __restrict__ out, int n) {
    __shared__ float ws[D * NC];
    int tid = threadIdx.x;
    for (int i = tid; i < D * NC; i += 256) ws[i] = Wout[i];
    __syncthreads();
    int node = blockIdx.x * 32 + (tid >> 3);
    int c = tid & 7;
    if (node >= n) return;
    float acc = bout[c];
    const __half* hrow = &h[(size_t)node * D];
#pragma unroll
    for (int k8 = 0; k8 < 16; ++k8) {
        float4 raw = *(const float4*)&hrow[k8 * 8];
        const __half2* hp = (const __half2*)&raw;
#pragma unroll
        for (int q = 0; q < 4; ++q) {
            float2 f = __half22float2(hp[q]);
            int k = k8 * 8 + 2 * q;
            acc += f.x * ws[k * NC + c] + f.y * ws[(k + 1) * NC + c];
        }
    }
    float m = acc;
#pragma unroll
    for (int off = 1; off < 8; off <<= 1) m = fmaxf(m, __shfl_xor(m, off));
    float e = __expf(acc - m);
    float ssum = e;
#pragma unroll
    for (int off = 1; off < 8; off <<= 1) ssum += __shfl_xor(ssum, off);
    out[(size_t)node * NC + c] = e / ssum;
}

// ---------------- launch ----------------
extern "C" void kernel_launch(void* const* d_in, const int* in_sizes, int n_in,
                              void* d_out, int out_size, void* d_ws, size_t ws_size,
                              hipStream_t stream) {
    const float* x    = (const float*)d_in[0];
    const int*   ei   = (const int*)d_in[1];   // [2][NE]: row 0 = src, row 1 = dst
    const float* W1   = (const float*)d_in[2];
    const float* b1   = (const float*)d_in[3];
    const float* W2   = (const float*)d_in[4];
    const float* b2   = (const float*)d_in[5];
    const float* Wout = (const float*)d_in[6];
    const float* bout = (const float*)d_in[7];
    float* out = (float*)d_out;

    size_t off = 0;
    char* base = (char*)d_ws;
    auto alloc = [&](size_t bytes) -> void* {
        void* p = base + off;
        off += (bytes + 255) & ~(size_t)255;
        return p;
    };
    int*    cnt      = (int*)alloc((size_t)NN * 4);
    int*    rowstart = (int*)alloc((size_t)NN * 4);
    int*    gcount   = (int*)alloc((size_t)(NBUCK + 1) * 4);
    int*    bstart   = (int*)alloc((size_t)(NBUCK + 1) * 4);
    int*    bcursor  = (int*)alloc((size_t)(NBUCK + 1) * 4);
    int*    csr      = (int*)alloc((size_t)NE * 4);
    float*  dinv     = (float*)alloc((size_t)NN * 4);
    __half* wt1      = (__half*)alloc((size_t)D * D * 2);
    __half* wt2      = (__half*)alloc((size_t)D * D * 2);
    __half* h16a     = (__half*)alloc((size_t)NN * D * 2);
    __half* h16f     = (__half*)alloc((size_t)NN * D * 2);
    __half* h16b     = (__half*)alloc((size_t)NN * D * 2);
    int2*   staged   = (int2*)h16f;  // alias: consumed by k_bfill before h16f is written
    if (off > ws_size) return;  // workspace too small; fail visibly

    const int* src = ei;
    const int* dst = ei + NE;

    // ---- CSR build via bucketed counting sort ----
    int bin_grid = (NE + CHUNK - 1) / CHUNK;  // 391
    k_zero<<<2, 256, 0, stream>>>(gcount, NBUCK);
    k_bhist<<<bin_grid, 256, 0, stream>>>(dst, gcount, NE);
    k_bscan<<<1, 512, 0, stream>>>(gcount, bstart, bcursor);
    k_bscatter<<<bin_grid, 256, 0, stream>>>(src, dst, bcursor, staged, NE);
    k_bfill<<<NBUCK, 256, 0, stream>>>(staged, bstart, rowstart, cnt, dinv, csr);

    // ---- weight prep ----
    k_cvtw<<<1, 256, 0, stream>>>(W1, wt1);
    k_cvtw<<<1, 256, 0, stream>>>(W2, wt2);

    int gemm_grid = NN / 32;       // 3125 exactly
    int agg_grid = NN / 4;         // 25000 exactly
    // layer 1
    k_mgemm<true><<<gemm_grid, 256, 0, stream>>>(x, wt1, dinv, h16a);
    k_agg<<<agg_grid, 256, 0, stream>>>(h16a, rowstart, cnt, csr, dinv, b1, h16f, NN);
    // layer 2
    k_mgemm<false><<<gemm_grid, 256, 0, stream>>>(h16f, wt2, dinv, h16a);
    k_agg<<<agg_grid, 256, 0, stream>>>(h16a, rowstart, cnt, csr, dinv, b2, h16b, NN);
    // output projection + softmax
    k_out<<<(NN + 31) / 32, 256, 0, stream>>>(h16b, Wout, bout, out, NN);
}